// Round 8
// baseline (252.267 us; speedup 1.0000x reference)
//
#include <hip/hip_runtime.h>
#include <hip/hip_cooperative_groups.h>

#define NCELL 24576      // 128*192 feature cells
#define NTOT  221184     // NCELL * 9
#define NBIN13 8192      // 13-bit score-key histogram bins
#define TOPN  6000
#define POSTN 300
#define NPADR 6016       // padded candidate count (94 words of 64)
#define NW    94         // suppression-mask words per row
#define CW    8          // words per scan chunk (512 ranks)
#define NCHUNK 12        // ceil(94/8)
#define NCB   16         // compaction slices
#define SLOT  1024       // cbuf slot per slice
#define CAP2  (NCB*SLOT) // 16384 total cbuf slots

namespace cg = cooperative_groups;

// ------------- fused decode + histogram + T-find + compact (cooperative, 96 blocks) -----------
// phase0: zero ghist/gslice (replaces hipMemsetAsync). grid.sync.
// phase1: decode boxes+keys (keys stay in 9 registers), LDS hist, flush nonzero bins. grid.sync.
// phase2: per-block T-find from summed ghist (same algorithm as old compactT, resized to 256t).
// phase3: compact own keys from REGISTERS into slotted cbuf via global slice counters
//         (gslice doubles as meta16; cbuf tails are NOT padded -- rankscatter guards by count).
__global__ __launch_bounds__(256) void decode_compact_kernel(
        const float* __restrict__ scores, const float* __restrict__ deltas,
        const float* __restrict__ iminfo, float4* __restrict__ boxes,
        unsigned* __restrict__ ghist, unsigned* __restrict__ gslice,
        unsigned long long* __restrict__ cbuf) {
#pragma clang fp contract(off)
    cg::grid_group grid = cg::this_grid();
    __shared__ unsigned lhist[NBIN13];     // 32 KB
    __shared__ unsigned psum[256];
    __shared__ unsigned sB, sAbove, sT;
    int tid = threadIdx.x;
    int c = blockIdx.x * 256 + tid;        // cell id; 96*256 == NCELL exactly
    // ---- phase 0: zero global accumulators (disjoint threads) + local hist ----
    if (c < NBIN13) ghist[c] = 0u;
    if (c < NCB) gslice[c] = 0u;
    for (int b = tid; b < NBIN13; b += 256) lhist[b] = 0u;
    grid.sync();
    // ---- phase 1: decode + register keys + LDS hist ----
    unsigned keyr[9];
    {
        const float AW[9] = {184.f,368.f,736.f,128.f,256.f,512.f, 88.f,176.f,352.f};
        const float AH[9] = { 96.f,192.f,384.f,128.f,256.f,512.f,176.f,352.f,704.f};
        float sx = (float)((c >> 7) << 4);   // (c/128)*16  -- 'ij' meshgrid quirk
        float sy = (float)((c & 127) << 4);  // (c%128)*16
        float imh = iminfo[0], imw = iminfo[1], ims = iminfo[2];
        float xhi = imw - 1.0f, yhi = imh - 1.0f;
        float ms = 16.0f * ims;
        float ctrx = sx + 8.0f, ctry = sy + 8.0f;
        const float* sbase = scores + 9 * NCELL + c;
        const float* dbase = deltas + c;
#pragma unroll
        for (int a = 0; a < 9; ++a) {
            float sc = sbase[a * NCELL];
            float dx = dbase[(4 * a + 0) * NCELL];
            float dy = dbase[(4 * a + 1) * NCELL];
            float dw = dbase[(4 * a + 2) * NCELL];
            float dh = dbase[(4 * a + 3) * NCELL];
            float pcx = dx * AW[a] + ctrx;
            float pcy = dy * AH[a] + ctry;
            float pw = expf(dw) * AW[a];
            float ph = expf(dh) * AH[a];
            float x1 = pcx - 0.5f * pw;
            float y1 = pcy - 0.5f * ph;
            float x2 = pcx + 0.5f * pw;
            float y2 = pcy + 0.5f * ph;
            x1 = fminf(fmaxf(x1, 0.0f), xhi);
            x2 = fminf(fmaxf(x2, 0.0f), xhi);
            y1 = fminf(fmaxf(y1, 0.0f), yhi);
            y2 = fminf(fmaxf(y2, 0.0f), yhi);
            bool valid = ((x2 - x1 + 1.0f) >= ms) && ((y2 - y1 + 1.0f) >= ms);
            unsigned u = __float_as_uint(sc);
            unsigned key = (u & 0x80000000u) ? ~u : (u | 0x80000000u);
            if (!valid) key = 0x007FFFFFu;   // sort key of -inf
            boxes[a * NCELL + c] = make_float4(x1, y1, x2, y2);
            keyr[a] = key;
            atomicAdd(&lhist[key >> 19], 1u);
        }
    }
    __syncthreads();
    for (int b = tid; b < NBIN13; b += 256) {
        unsigned v = lhist[b];
        if (v) atomicAdd(&ghist[b], v);      // device-scope, cross-XCD safe
    }
    grid.sync();
    // ---- phase 2: T-find (cum(>=T) >= 6000, cum(>T) < 6000); identical in every block ----
    {
        const uint4* gh4 = (const uint4*)ghist;
        uint4* h4 = (uint4*)lhist;
        for (int q = tid; q < NBIN13 / 4; q += 256) h4[q] = gh4[q];
    }
    __syncthreads();
    unsigned s = 0;
#pragma unroll
    for (int q = 0; q < 32; ++q) s += lhist[tid * 32 + q];
    psum[tid] = s;
    __syncthreads();
    if (tid < 64) {
        unsigned c0 = psum[tid * 4 + 0], c1 = psum[tid * 4 + 1];
        unsigned c2 = psum[tid * 4 + 2], c3 = psum[tid * 4 + 3];
        unsigned ls = c0 + c1 + c2 + c3;
        unsigned v = ls;
#pragma unroll
        for (int o = 1; o < 64; o <<= 1) {
            unsigned t = __shfl_down(v, o, 64);
            if (tid + o < 64) v += t;
        }
        unsigned sufExcl = v - ls;
        unsigned a3 = sufExcl;
        unsigned a2 = a3 + c3;
        unsigned a1 = a2 + c2;
        unsigned a0 = a1 + c1;
        if (a0 < TOPN && a0 + c0 >= TOPN) { sB = tid * 4 + 0; sAbove = a0; }
        if (a1 < TOPN && a1 + c1 >= TOPN) { sB = tid * 4 + 1; sAbove = a1; }
        if (a2 < TOPN && a2 + c2 >= TOPN) { sB = tid * 4 + 2; sAbove = a2; }
        if (a3 < TOPN && a3 + c3 >= TOPN) { sB = tid * 4 + 3; sAbove = a3; }
    }
    __syncthreads();
    if (tid < 32) {
        unsigned B = sB, above = sAbove;
        unsigned h = lhist[B * 32 + tid];
        unsigned v = h;
#pragma unroll
        for (int o = 1; o < 32; o <<= 1) {
            unsigned t = __shfl_down(v, o, 64);
            if (tid + o < 32) v += t;
        }
        unsigned sufExcl = v - h;
        unsigned ab = above + sufExcl;
        if (ab < TOPN && ab + h >= TOPN) sT = B * 32 + tid;
    }
    __syncthreads();
    unsigned T = sT;
    // ---- phase 3: compact own keys (registers) into slotted cbuf (n = c*9+a, no div) ----
#pragma unroll
    for (int a = 0; a < 9; ++a) {
        unsigned key = keyr[a];
        if ((key >> 19) >= T) {
            int m = a * NCELL + c;
            int slice = m / (NTOT / NCB);          // const-div -> magic mul
            unsigned lp = atomicAdd(&gslice[slice], 1u);
            if (lp < SLOT) {
                unsigned n = (unsigned)(c * 9 + a);
                cbuf[((unsigned)slice << 10) + lp] =
                    ((unsigned long long)key << 32) | (unsigned long long)(~n);
            }
        }
    }
}

// ---------------- rank by counting + scatter over slotted cbuf (count-guarded tails) ----------
__global__ __launch_bounds__(256) void rankscatter_kernel(const unsigned long long* __restrict__ cbuf,
                                                          const unsigned* __restrict__ meta16,
                                                          const float4* __restrict__ boxes,
                                                          float4* __restrict__ sortedbox) {
    __shared__ unsigned long long jk[512];
    __shared__ unsigned scnt[NCB];
    int tid = threadIdx.x;
    if (tid < NCB) {
        unsigned m = meta16[tid];
        scnt[tid] = (m > SLOT) ? SLOT : m;
    }
    __syncthreads();
    int i = blockIdx.x * 32 + (tid >> 3);
    int slice = tid & 7;
    // tail slots beyond a slice's count hold poison -> treat as 0 (old code zero-padded)
    unsigned long long ki = ((unsigned)(i & 1023) < scnt[i >> 10]) ? cbuf[i] : 0ULL;
    unsigned cr = 0;
    for (int jt = 0; jt < CAP2 / 512; ++jt) {
        int b = jt >> 1;
        unsigned cb = scnt[b];
        if ((jt & 1) ? (cb <= 512u) : (cb == 0u)) continue;   // block-uniform skip
        __syncthreads();
        for (int q = tid; q < 512; q += 256) {
            unsigned p = ((unsigned)(jt & 1) << 9) + (unsigned)q;
            jk[q] = (p < cb) ? cbuf[(jt << 9) + q] : 0ULL;
        }
        __syncthreads();
#pragma unroll 8
        for (int j = 0; j < 64; ++j) cr += (jk[slice + (j << 3)] > ki) ? 1u : 0u;
    }
    cr += __shfl_down(cr, 4, 8);
    cr += __shfl_down(cr, 2, 8);
    cr += __shfl_down(cr, 1, 8);
    if (slice == 0 && ki != 0ULL && cr < NPADR) {
        unsigned n = ~(unsigned)ki;
        unsigned m = (n % 9u) * (unsigned)NCELL + (n / 9u);
        sortedbox[cr] = boxes[m];
    }
}

// ---------------- all-pairs suppression matrix: word-per-thread ----------------
// grid (24, 94): blockIdx.y = 64-row i-tile; blockIdx.x = one 256-col j-tile.
// rowr: row-major words, only w >= row's diag word (inline-fold/B2 read those).
// diagw holds TRANSPOSED chunk-triangle 64x64 blocks: slot [(w<<9)+(qs<<6)+j] =
// column j of block (qs -> w), qs < w within the chunk. Exact-diag transpose -> diagT.
__global__ __launch_bounds__(256) void matrix_kernel(const float4* __restrict__ sortedbox,
                                                     unsigned long long* __restrict__ rowr,
                                                     unsigned long long* __restrict__ diagw,
                                                     unsigned long long* __restrict__ diagT) {
#pragma clang fp contract(off)
    __shared__ float4 jb[256];
    __shared__ float  ja[256];
    int tid = threadIdx.x;
    int lane = tid & 63, wave = tid >> 6;
    int i0 = blockIdx.y << 6;
    int i = i0 + lane;
    int w = (blockIdx.x << 2) + wave;
    int jbase = blockIdx.x << 8;
    unsigned long long word = 0ULL;

    if (jbase + 255 > i0) {                  // tile not entirely below diagonal
        int jg = jbase + tid;
        float4 v = (jg < NPADR) ? sortedbox[jg] : make_float4(0.f, 0.f, 0.f, 0.f);
        jb[tid] = v;
        ja[tid] = (v.z - v.x) * (v.w - v.y);
        __syncthreads();
        if (w < NW && ((w << 6) + 63) > i) { // this word has bits above the diagonal
            float4 bi = sortedbox[i];
            float ai = (bi.z - bi.x) * (bi.w - bi.y);
            int jl0 = wave << 6;
            int jg0 = (w << 6);
#pragma unroll 8
            for (int j = 0; j < 64; ++j) {
                float4 bj = jb[jl0 + j];
                float aj = ja[jl0 + j];
                float iw = fminf(bi.z, bj.z) - fmaxf(bi.x, bj.x);
                float ih = fminf(bi.w, bj.w) - fmaxf(bi.y, bj.y);
                iw = fmaxf(iw, 0.0f);
                ih = fmaxf(ih, 0.0f);
                float inter = iw * ih;
                float denom = fmaxf(ai + aj - inter, 1e-9f);
                bool sup = (jg0 + j > i) && (inter / denom > 0.7f);
                word |= (unsigned long long)sup << j;
            }
        }
    }
    if (w < NW) {
        if (w >= (i >> 6))                   // above/diag words only (sub-diag never read)
            rowr[(size_t)i * NW + w] = word;
        if ((i >> 9) == (w >> 3) && w >= (i >> 6)) {
            // chunk-region block at/above diagonal: transpose via 64 ballots
            unsigned long long col = 0ULL;
#pragma unroll
            for (int jbit = 0; jbit < 64; ++jbit) {
                unsigned long long m = __ballot((word >> jbit) & 1ULL);
                if (lane == jbit) col = m;
            }
            if (w == (i >> 6))
                diagT[((size_t)w << 6) + lane] = col;         // exact diag block
            else
                diagw[((size_t)w << 9) + (i & 511)] = col;    // transposed triangle block
        }
    }
}

// ---------------- greedy scan: single barrier per chunk, inline kept-fold -------------------
// 512 threads. Per chunk c (ONE barrier at end):
//   wave0 : inline fold kept(c-1) -> chunk-c words (8 rows x 8 words across 64 lanes, one
//           pipelined global round + 3 shfl_xor), then transposed-propagate fixed-point
//           resolve (R7 body). No gm writes (chunk-c gm dead after A(c)).
//   waves1-7 pool: stage chunk c+1 (transposed triangle cblk + ldsT, 16B), then B2:
//           kept(c-1) rows -> gm[words >= wbase+CW].
// Coverage: kept(c-1)->chunk c inline@A(c); kept(k<=c-2)->chunk c via B2@A(k+1) (targets
// >= chunk k+2). Races: B2 atomicOrs only words >= wbase+CW; wave0 writes keptArr[kB..)
// while pool reads [kA,kB) -- disjoint; staged buffers double-buffered.
__global__ __launch_bounds__(512) void scan_kernel(const unsigned long long* __restrict__ rowr,
                                                   const unsigned long long* __restrict__ diagw,
                                                   const unsigned long long* __restrict__ diagT,
                                                   const float4* __restrict__ sortedbox,
                                                   float* __restrict__ out) {
    __shared__ __align__(16) unsigned long long cblk[2][CW * 512]; // 64 KB transposed blocks
    __shared__ __align__(16) unsigned long long ldsT[2][CW * 64];  // 8 KB diagT dbuf
    __shared__ unsigned long long gm[128];
    __shared__ int keptArr[POSTN];
    __shared__ int s_kept, s_done;
    int tid = threadIdx.x;
    int lane = tid & 63, wave = tid >> 6;

    if (tid < 128) gm[tid] = (tid == 93) ? ~((1ULL << 48) - 1) : 0ULL; // ranks>=6000 dead
    if (tid == 0) { s_kept = 0; s_done = 0; }
    // stage chunk 0: triangle cblkT + ldsT, 16B vectorized (all 512 threads)
    for (int pe = tid; pe < CW * 256; pe += 512) {
        int q = pe >> 8, r = (pe & 255) << 1;
        if (q > (r >> 6))
            *(ulonglong2*)&cblk[0][(q << 9) + r] =
                *(const ulonglong2*)&diagw[((size_t)q << 9) + r];
    }
    for (int pe = tid; pe < CW * 32; pe += 512) {
        int e = pe << 1;
        *(ulonglong2*)&ldsT[0][e] = *(const ulonglong2*)&diagT[e];
    }
    __syncthreads();

    int kA = 0;  // kept count before chunk c-1's resolve
    int kB = 0;  // kept count before chunk c's resolve
    for (int c = 0; c < NCHUNK; ++c) {
        int buf = c & 1, nbuf = buf ^ 1;
        int wbase = c * CW;
        if (wave == 0) {
            // ---- inline fold: kept(c-1) rows -> chunk-c words (replaces B1 + barrier) ----
            unsigned long long inl = 0ULL;
            {
                int q = lane & 7;
                if (wbase + q < NW)
                    for (int s = kA + (lane >> 3); s < kB; s += 8)
                        inl |= rowr[(size_t)keptArr[s] * NW + wbase + q];
                inl |= __shfl_xor(inl, 8, 64);
                inl |= __shfl_xor(inl, 16, 64);
                inl |= __shfl_xor(inl, 32, 64);
                // lane now holds the complete kept(c-1) mask for word (lane&7)
            }
            // ---- resolve chunk c: transposed propagate, register chunk state ----
            unsigned long long dgT[CW];
            unsigned long long gml[CW];
#pragma unroll
            for (int q = 0; q < CW; ++q) dgT[q] = ldsT[buf][(q << 6) + lane];
#pragma unroll
            for (int q = 0; q < CW; ++q) gml[q] = (wbase + q < NW) ? gm[wbase + q] : ~0ULL;
            unsigned long long lowmask = (1ULL << lane) - 1ULL;
            unsigned chunk_sup = 0;      // bit t: this lane suppressed in word t by chunk kept
            int kept = kB;
            int done = 0;
            int qmax = (NW - wbase < CW) ? (NW - wbase) : CW;
            for (int q = 0; q < qmax; ++q) {
                unsigned long long csup = __ballot((chunk_sup >> q) & 1u);
                unsigned long long live = ~(gml[q] | __shfl(inl, q, 64) | csup);
                if (wbase + q == NW - 1) live &= (1ULL << 48) - 1;
                if (!live) continue;
                bool alive = (live >> lane) & 1ULL;
                unsigned long long x = live;
                for (;;) {
                    bool sup = (dgT[q] & x & lowmask) != 0ULL;
                    unsigned long long xn = __ballot(alive && !sup);
                    if (xn == x) break;
                    x = xn;
                }
                unsigned long long kb = x;
                if (kb) {
                    int nk = __popcll(kb);
                    int myr = __popcll(kb & lowmask);
                    if (((kb >> lane) & 1ULL) && (kept + myr < POSTN))
                        keptArr[kept + myr] = ((wbase + q) << 6) + lane;
                    kept += nk;
                    if (kept >= POSTN) { kept = POSTN; done = 1; break; }
                    if (q < CW - 1) {
                        // one parallel LDS round: lane j tests column j of each later word
                        unsigned long long pr[CW];
#pragma unroll
                        for (int t = 0; t < CW; ++t)
                            pr[t] = cblk[buf][(t << 9) + (q << 6) + lane];
#pragma unroll
                        for (int t = 0; t < CW; ++t)
                            if (t > q && (pr[t] & kb)) chunk_sup |= 1u << t;
                    }
                }
            }
            if (lane == 0) { s_kept = kept; s_done = done; }
        } else {
            // ---- waves 1-7 pool: stage chunk c+1 (transposed), then B2 ----
            int t = tid - 64;                          // 0..447
            if (c + 1 < NCHUNK) {
                int wb2 = wbase + CW;
                for (int pe = t; pe < CW * 256; pe += 448) {
                    int q = pe >> 8, r = (pe & 255) << 1;
                    if (q > (r >> 6)) {                // triangle only (never read otherwise)
                        ulonglong2 v = make_ulonglong2(0ULL, 0ULL);
                        if (wb2 + q < NW && wb2 + (r >> 6) < NW)   // target+source words valid
                            v = *(const ulonglong2*)&diagw[((size_t)(wb2 + q) << 9) + r];
                        *(ulonglong2*)&cblk[nbuf][(q << 9) + r] = v;
                    }
                }
                for (int pe = t; pe < CW * 32; pe += 448) {
                    int e = pe << 1, q = e >> 6;
                    ulonglong2 v = make_ulonglong2(0ULL, 0ULL);
                    if (wb2 + q < NW) v = *(const ulonglong2*)&diagT[((size_t)wb2 << 6) + e];
                    *(ulonglong2*)&ldsT[nbuf][e] = v;
                }
            }
            {
                // B2: kept(c-1) rows into gm[words >= wbase+CW], 16B vectorized
                int w2 = wbase + CW;
                int nw2 = NW - w2;                     // always even
                int nr2 = kB - kA;
                if (c > 0 && nr2 > 0 && nw2 > 0) {
                    int npair = nw2 >> 1;
                    int tot = nr2 * npair;
                    for (int idx = t; idx < tot; idx += 448) {
                        int s = idx / npair, po = idx - s * npair;
                        int row = keptArr[kA + s];
                        ulonglong2 v = *(const ulonglong2*)&rowr[(size_t)row * NW + w2 + (po << 1)];
                        if (v.x) atomicOr(&gm[w2 + (po << 1)], v.x);
                        if (v.y) atomicOr(&gm[w2 + (po << 1) + 1], v.y);
                    }
                }
            }
        }
        __syncthreads();
        kA = kB;
        kB = s_kept;
        if (s_done != 0 || c == NCHUNK - 1) break;
    }
    __syncthreads();

    int kept = s_kept;
    for (int k = tid; k < POSTN; k += 512) {
        float4 bb = make_float4(0.f, 0.f, 0.f, 0.f);
        if (k < kept) bb = sortedbox[keptArr[k]];
        out[k * 5 + 0] = 0.0f;
        out[k * 5 + 1] = bb.x;
        out[k * 5 + 2] = bb.y;
        out[k * 5 + 3] = bb.z;
        out[k * 5 + 4] = bb.w;
    }
}

extern "C" void kernel_launch(void* const* d_in, const int* in_sizes, int n_in,
                              void* d_out, int out_size, void* d_ws, size_t ws_size,
                              hipStream_t stream) {
    const float* scores = (const float*)d_in[0];
    const float* deltas = (const float*)d_in[1];
    const float* iminfo = (const float*)d_in[2];
    char* w = (char*)d_ws;
    // workspace (~5.5 MB). rowr ALIASES boxes (dead after rankscatter).
    float4*   boxes = (float4*)w;                                   // [0, 3538944)
    unsigned long long* rowr = (unsigned long long*)w;              // [0, 4524032) alias
    unsigned* gslice = (unsigned*)(w + 4786176);                    // 16 words (= meta16)
    unsigned long long* cbuf = (unsigned long long*)(w + 4786240);  // [4786240, 4917312)
    float4* sortedbox = (float4*)(w + 4917312);                     // [4917312, 5013568)
    unsigned long long* diagw = (unsigned long long*)(w + 5013568); // [5013568, 5398592)
    unsigned long long* diagT = (unsigned long long*)(w + 5398592); // [5398592, 5446720)
    unsigned* ghist = (unsigned*)(w + 5446720);                     // [5446720, 5479488) 32KB
    float* out = (float*)d_out;

    void* kargs[] = { (void*)&scores, (void*)&deltas, (void*)&iminfo, (void*)&boxes,
                      (void*)&ghist, (void*)&gslice, (void*)&cbuf };
    hipLaunchCooperativeKernel(reinterpret_cast<void*>(&decode_compact_kernel),
                               dim3(96), dim3(256), kargs, 0u, stream);
    rankscatter_kernel<<<CAP2 / 32, 256, 0, stream>>>(cbuf, gslice, boxes, sortedbox);
    matrix_kernel<<<dim3(24, 94), 256, 0, stream>>>(sortedbox, rowr, diagw, diagT);
    scan_kernel<<<1, 512, 0, stream>>>(rowr, diagw, diagT, sortedbox, out);
}

// Round 9
// 136.557 us; speedup vs baseline: 1.8473x; 1.8473x over previous
//
#include <hip/hip_runtime.h>

#define NCELL 24576      // 128*192 feature cells
#define NTOT  221184     // NCELL * 9
#define NBIN13 8192      // 13-bit score-key histogram bins (LDS)
#define TOPN  6000
#define POSTN 300
#define NPADR 6016       // padded candidate count (94 words of 64)
#define NW    94         // suppression-mask words per row
#define CW    8          // words per scan chunk (512 ranks)
#define NCHUNK 12        // ceil(94/8)
#define NCB   16         // compaction blocks
#define SLOT  1024       // cbuf slot per compaction block
#define CAP2  (NCB*SLOT) // 16384 total cbuf slots

// ---------------- decode anchors + scores, build sort keys + fused global hist ----------------
// ghist must be zeroed (hipMemsetAsync) before this launch. Each block histograms its own
// 2304 keys in LDS, then flushes nonzero bins via device-scope atomicAdd.
// NOTE (R8 lesson): do NOT fuse these stages with hipLaunchCooperativeKernel -- grid.sync()
// on gfx950 under graph capture cost ~50us per sync (113us kernel, VALUBusy 0.6%, pure stall).
__global__ void decode_kernel(const float* __restrict__ scores,
                              const float* __restrict__ deltas,
                              const float* __restrict__ iminfo,
                              float4* __restrict__ boxes,
                              unsigned* __restrict__ skeys,
                              unsigned* __restrict__ ghist) {
#pragma clang fp contract(off)
    __shared__ unsigned lhist[NBIN13];     // 32 KB
    int tid = threadIdx.x;
    for (int b = tid; b < NBIN13; b += 256) lhist[b] = 0u;
    __syncthreads();
    int c = blockIdx.x * blockDim.x + tid;
    if (c < NCELL) {
        const float AW[9] = {184.f,368.f,736.f,128.f,256.f,512.f, 88.f,176.f,352.f};
        const float AH[9] = { 96.f,192.f,384.f,128.f,256.f,512.f,176.f,352.f,704.f};
        float sx = (float)((c >> 7) << 4);   // (c/128)*16  -- 'ij' meshgrid quirk
        float sy = (float)((c & 127) << 4);  // (c%128)*16
        float imh = iminfo[0], imw = iminfo[1], ims = iminfo[2];
        float xhi = imw - 1.0f, yhi = imh - 1.0f;
        float ms = 16.0f * ims;
        float ctrx = sx + 8.0f, ctry = sy + 8.0f;
        const float* sbase = scores + 9 * NCELL + c;
        const float* dbase = deltas + c;
#pragma unroll
        for (int a = 0; a < 9; ++a) {
            float sc = sbase[a * NCELL];
            float dx = dbase[(4 * a + 0) * NCELL];
            float dy = dbase[(4 * a + 1) * NCELL];
            float dw = dbase[(4 * a + 2) * NCELL];
            float dh = dbase[(4 * a + 3) * NCELL];
            float pcx = dx * AW[a] + ctrx;
            float pcy = dy * AH[a] + ctry;
            float pw = expf(dw) * AW[a];
            float ph = expf(dh) * AH[a];
            float x1 = pcx - 0.5f * pw;
            float y1 = pcy - 0.5f * ph;
            float x2 = pcx + 0.5f * pw;
            float y2 = pcy + 0.5f * ph;
            x1 = fminf(fmaxf(x1, 0.0f), xhi);
            x2 = fminf(fmaxf(x2, 0.0f), xhi);
            y1 = fminf(fmaxf(y1, 0.0f), yhi);
            y2 = fminf(fmaxf(y2, 0.0f), yhi);
            bool valid = ((x2 - x1 + 1.0f) >= ms) && ((y2 - y1 + 1.0f) >= ms);
            unsigned u = __float_as_uint(sc);
            unsigned key = (u & 0x80000000u) ? ~u : (u | 0x80000000u);
            if (!valid) key = 0x007FFFFFu;   // sort key of -inf
            boxes[a * NCELL + c] = make_float4(x1, y1, x2, y2);
            skeys[a * NCELL + c] = key;
            atomicAdd(&lhist[key >> 19], 1u);
        }
    }
    __syncthreads();
    for (int b = tid; b < NBIN13; b += 256) {
        unsigned v = lhist[b];
        if (v) atomicAdd(&ghist[b], v);      // device-scope, cross-XCD safe
    }
}

// ---------------- per-block T-find (from precomputed ghist) + slice compact (16 blocks) -------
__global__ __launch_bounds__(1024) void compactT_kernel(const unsigned* __restrict__ skeys,
                                                        const unsigned* __restrict__ ghist,
                                                        unsigned* __restrict__ meta16,
                                                        unsigned long long* __restrict__ cbuf) {
    __shared__ unsigned hist[NBIN13];      // 32 KB
    __shared__ unsigned psum[1024];
    __shared__ unsigned csum[256];
    __shared__ unsigned sB, sAbove, sT, sCount;
    int tid = threadIdx.x, bid = blockIdx.x;
    // load the finished histogram (2 x uint4 per thread)
    {
        const uint4* gh4 = (const uint4*)ghist;
        uint4* h4 = (uint4*)hist;
        for (int q = tid; q < NBIN13 / 4; q += 1024) h4[q] = gh4[q];
    }
    if (tid == 0) sCount = 0u;
    __syncthreads();
    // threshold T: cum(>=T) >= 6000, cum(>T) < 6000  (identical in every block)
    unsigned s = 0;
#pragma unroll
    for (int q = 0; q < 8; ++q) s += hist[tid * 8 + q];
    psum[tid] = s;
    __syncthreads();
    if (tid < 256)
        csum[tid] = psum[tid * 4] + psum[tid * 4 + 1] + psum[tid * 4 + 2] + psum[tid * 4 + 3];
    __syncthreads();
    if (tid < 64) {
        int lane = tid;
        unsigned c0 = csum[lane * 4 + 0], c1 = csum[lane * 4 + 1];
        unsigned c2 = csum[lane * 4 + 2], c3 = csum[lane * 4 + 3];
        unsigned ls = c0 + c1 + c2 + c3;
        unsigned v = ls;
#pragma unroll
        for (int o = 1; o < 64; o <<= 1) {
            unsigned t = __shfl_down(v, o, 64);
            if (lane + o < 64) v += t;
        }
        unsigned sufExcl = v - ls;
        unsigned a3 = sufExcl;
        unsigned a2 = a3 + c3;
        unsigned a1 = a2 + c2;
        unsigned a0 = a1 + c1;
        if (a0 < TOPN && a0 + c0 >= TOPN) { sB = lane * 4 + 0; sAbove = a0; }
        if (a1 < TOPN && a1 + c1 >= TOPN) { sB = lane * 4 + 1; sAbove = a1; }
        if (a2 < TOPN && a2 + c2 >= TOPN) { sB = lane * 4 + 2; sAbove = a2; }
        if (a3 < TOPN && a3 + c3 >= TOPN) { sB = lane * 4 + 3; sAbove = a3; }
    }
    __syncthreads();
    if (tid < 32) {
        unsigned B = sB, above = sAbove;
        unsigned h = hist[B * 32 + tid];
        unsigned v = h;
#pragma unroll
        for (int o = 1; o < 32; o <<= 1) {
            unsigned t = __shfl_down(v, o, 64);
            if (tid + o < 32) v += t;
        }
        unsigned sufExcl = v - h;
        unsigned ab = above + sufExcl;
        if (ab < TOPN && ab + h >= TOPN) sT = B * 32 + tid;
    }
    __syncthreads();
    // compact OWN slice into private slot (LDS-local positions, no global atomics)
    unsigned T = sT;
    int base = bid * (NTOT / NCB);                  // 13824-element slice
    const uint4* s4b = (const uint4*)(skeys + base);
    for (int q = tid; q < (NTOT / NCB) / 4; q += 1024) {
        uint4 u = s4b[q];
        unsigned k4[4] = {u.x, u.y, u.z, u.w};
#pragma unroll
        for (int k = 0; k < 4; ++k) {
            if ((k4[k] >> 19) >= T) {
                unsigned lp = atomicAdd(&sCount, 1u);
                if (lp < SLOT) {
                    int m = base + 4 * q + k;
                    unsigned n = (unsigned)((m % NCELL) * 9 + (m / NCELL));
                    cbuf[(bid << 10) + lp] =
                        ((unsigned long long)k4[k] << 32) | (unsigned long long)(~n);
                }
            }
        }
    }
    __syncthreads();
    unsigned cnt = sCount; if (cnt > SLOT) cnt = SLOT;
    for (int e = cnt + tid; e < SLOT; e += 1024) cbuf[(bid << 10) + e] = 0ULL;  // pad
    if (tid == 0) meta16[bid] = cnt;
}

// ---------------- rank by counting + scatter over slotted cbuf ----------------
__global__ __launch_bounds__(256) void rankscatter_kernel(const unsigned long long* __restrict__ cbuf,
                                                          const unsigned* __restrict__ meta16,
                                                          const float4* __restrict__ boxes,
                                                          float4* __restrict__ sortedbox) {
    __shared__ unsigned long long jk[512];
    __shared__ unsigned scnt[NCB];
    int tid = threadIdx.x;
    if (tid < NCB) scnt[tid] = meta16[tid];
    __syncthreads();
    int i = blockIdx.x * 32 + (tid >> 3);
    int slice = tid & 7;
    unsigned long long ki = cbuf[i];
    unsigned cr = 0;
    for (int jt = 0; jt < CAP2 / 512; ++jt) {
        int b = jt >> 1;
        unsigned cb = scnt[b];
        if ((jt & 1) ? (cb <= 512u) : (cb == 0u)) continue;   // block-uniform skip
        __syncthreads();
        for (int q = tid; q < 512; q += 256) jk[q] = cbuf[(jt << 9) + q];
        __syncthreads();
#pragma unroll 8
        for (int j = 0; j < 64; ++j) cr += (jk[slice + (j << 3)] > ki) ? 1u : 0u;
    }
    cr += __shfl_down(cr, 4, 8);
    cr += __shfl_down(cr, 2, 8);
    cr += __shfl_down(cr, 1, 8);
    if (slice == 0 && ki != 0ULL && cr < NPADR) {
        unsigned n = ~(unsigned)ki;
        unsigned m = (n % 9u) * (unsigned)NCELL + (n / 9u);
        sortedbox[cr] = boxes[m];
    }
}

// ---------------- all-pairs suppression matrix: word-per-thread ----------------
// grid (24, 94): blockIdx.y = 64-row i-tile; blockIdx.x = one 256-col j-tile.
// rowr: row-major words, only w >= row's diag word (inline-fold/B2 read those).
// diagw holds TRANSPOSED chunk-triangle 64x64 blocks: slot [(w<<9)+(qs<<6)+j] =
// column j of block (qs -> w), qs < w within the chunk. Exact-diag transpose -> diagT.
__global__ __launch_bounds__(256) void matrix_kernel(const float4* __restrict__ sortedbox,
                                                     unsigned long long* __restrict__ rowr,
                                                     unsigned long long* __restrict__ diagw,
                                                     unsigned long long* __restrict__ diagT) {
#pragma clang fp contract(off)
    __shared__ float4 jb[256];
    __shared__ float  ja[256];
    int tid = threadIdx.x;
    int lane = tid & 63, wave = tid >> 6;
    int i0 = blockIdx.y << 6;
    int i = i0 + lane;
    int w = (blockIdx.x << 2) + wave;
    int jbase = blockIdx.x << 8;
    unsigned long long word = 0ULL;

    if (jbase + 255 > i0) {                  // tile not entirely below diagonal
        int jg = jbase + tid;
        float4 v = (jg < NPADR) ? sortedbox[jg] : make_float4(0.f, 0.f, 0.f, 0.f);
        jb[tid] = v;
        ja[tid] = (v.z - v.x) * (v.w - v.y);
        __syncthreads();
        if (w < NW && ((w << 6) + 63) > i) { // this word has bits above the diagonal
            float4 bi = sortedbox[i];
            float ai = (bi.z - bi.x) * (bi.w - bi.y);
            int jl0 = wave << 6;
            int jg0 = (w << 6);
#pragma unroll 8
            for (int j = 0; j < 64; ++j) {
                float4 bj = jb[jl0 + j];
                float aj = ja[jl0 + j];
                float iw = fminf(bi.z, bj.z) - fmaxf(bi.x, bj.x);
                float ih = fminf(bi.w, bj.w) - fmaxf(bi.y, bj.y);
                iw = fmaxf(iw, 0.0f);
                ih = fmaxf(ih, 0.0f);
                float inter = iw * ih;
                float denom = fmaxf(ai + aj - inter, 1e-9f);
                bool sup = (jg0 + j > i) && (inter / denom > 0.7f);
                word |= (unsigned long long)sup << j;
            }
        }
    }
    if (w < NW) {
        if (w >= (i >> 6))                   // above/diag words only (sub-diag never read)
            rowr[(size_t)i * NW + w] = word;
        if ((i >> 9) == (w >> 3) && w >= (i >> 6)) {
            // chunk-region block at/above diagonal: transpose via 64 ballots
            unsigned long long col = 0ULL;
#pragma unroll
            for (int jbit = 0; jbit < 64; ++jbit) {
                unsigned long long m = __ballot((word >> jbit) & 1ULL);
                if (lane == jbit) col = m;
            }
            if (w == (i >> 6))
                diagT[((size_t)w << 6) + lane] = col;         // exact diag block
            else
                diagw[((size_t)w << 9) + (i & 511)] = col;    // transposed triangle block
        }
    }
}

// ---------------- greedy scan: single barrier per chunk, inline kept-fold -------------------
// 512 threads. Per chunk c (ONE barrier at end):
//   wave0 : inline fold kept(c-1) -> chunk-c words (8 rows x 8 words across 64 lanes, one
//           pipelined global round + 3 shfl_xor), then transposed-propagate fixed-point
//           resolve. No gm writes (chunk-c gm dead after A(c)).
//   waves1-7 pool: stage chunk c+1 (transposed triangle cblk + ldsT, 16B), then B2:
//           kept(c-1) rows -> gm[words >= wbase+CW].
// Coverage: kept(c-1)->chunk c inline@A(c); kept(k<=c-2)->chunk c via B2@A(k+1) (targets
// >= chunk k+2). Races: B2 atomicOrs only words >= wbase+CW; wave0 writes keptArr[kB..)
// while pool reads [kA,kB) -- disjoint; staged buffers double-buffered.
__global__ __launch_bounds__(512) void scan_kernel(const unsigned long long* __restrict__ rowr,
                                                   const unsigned long long* __restrict__ diagw,
                                                   const unsigned long long* __restrict__ diagT,
                                                   const float4* __restrict__ sortedbox,
                                                   float* __restrict__ out) {
    __shared__ __align__(16) unsigned long long cblk[2][CW * 512]; // 64 KB transposed blocks
    __shared__ __align__(16) unsigned long long ldsT[2][CW * 64];  // 8 KB diagT dbuf
    __shared__ unsigned long long gm[128];
    __shared__ int keptArr[POSTN];
    __shared__ int s_kept, s_done;
    int tid = threadIdx.x;
    int lane = tid & 63, wave = tid >> 6;

    if (tid < 128) gm[tid] = (tid == 93) ? ~((1ULL << 48) - 1) : 0ULL; // ranks>=6000 dead
    if (tid == 0) { s_kept = 0; s_done = 0; }
    // stage chunk 0: triangle cblkT + ldsT, 16B vectorized (all 512 threads)
    for (int pe = tid; pe < CW * 256; pe += 512) {
        int q = pe >> 8, r = (pe & 255) << 1;
        if (q > (r >> 6))
            *(ulonglong2*)&cblk[0][(q << 9) + r] =
                *(const ulonglong2*)&diagw[((size_t)q << 9) + r];
    }
    for (int pe = tid; pe < CW * 32; pe += 512) {
        int e = pe << 1;
        *(ulonglong2*)&ldsT[0][e] = *(const ulonglong2*)&diagT[e];
    }
    __syncthreads();

    int kA = 0;  // kept count before chunk c-1's resolve
    int kB = 0;  // kept count before chunk c's resolve
    for (int c = 0; c < NCHUNK; ++c) {
        int buf = c & 1, nbuf = buf ^ 1;
        int wbase = c * CW;
        if (wave == 0) {
            // ---- inline fold: kept(c-1) rows -> chunk-c words (replaces B1 + barrier) ----
            unsigned long long inl = 0ULL;
            {
                int q = lane & 7;
                if (wbase + q < NW)
                    for (int s = kA + (lane >> 3); s < kB; s += 8)
                        inl |= rowr[(size_t)keptArr[s] * NW + wbase + q];
                inl |= __shfl_xor(inl, 8, 64);
                inl |= __shfl_xor(inl, 16, 64);
                inl |= __shfl_xor(inl, 32, 64);
                // lane now holds the complete kept(c-1) mask for word (lane&7)
            }
            // ---- resolve chunk c: transposed propagate, register chunk state ----
            unsigned long long dgT[CW];
            unsigned long long gml[CW];
#pragma unroll
            for (int q = 0; q < CW; ++q) dgT[q] = ldsT[buf][(q << 6) + lane];
#pragma unroll
            for (int q = 0; q < CW; ++q) gml[q] = (wbase + q < NW) ? gm[wbase + q] : ~0ULL;
            unsigned long long lowmask = (1ULL << lane) - 1ULL;
            unsigned chunk_sup = 0;      // bit t: this lane suppressed in word t by chunk kept
            int kept = kB;
            int done = 0;
            int qmax = (NW - wbase < CW) ? (NW - wbase) : CW;
            for (int q = 0; q < qmax; ++q) {
                unsigned long long csup = __ballot((chunk_sup >> q) & 1u);
                unsigned long long live = ~(gml[q] | __shfl(inl, q, 64) | csup);
                if (wbase + q == NW - 1) live &= (1ULL << 48) - 1;
                if (!live) continue;
                bool alive = (live >> lane) & 1ULL;
                unsigned long long x = live;
                for (;;) {
                    bool sup = (dgT[q] & x & lowmask) != 0ULL;
                    unsigned long long xn = __ballot(alive && !sup);
                    if (xn == x) break;
                    x = xn;
                }
                unsigned long long kb = x;
                if (kb) {
                    int nk = __popcll(kb);
                    int myr = __popcll(kb & lowmask);
                    if (((kb >> lane) & 1ULL) && (kept + myr < POSTN))
                        keptArr[kept + myr] = ((wbase + q) << 6) + lane;
                    kept += nk;
                    if (kept >= POSTN) { kept = POSTN; done = 1; break; }
                    if (q < CW - 1) {
                        // one parallel LDS round: lane j tests column j of each later word
                        unsigned long long pr[CW];
#pragma unroll
                        for (int t = 0; t < CW; ++t)
                            pr[t] = cblk[buf][(t << 9) + (q << 6) + lane];
#pragma unroll
                        for (int t = 0; t < CW; ++t)
                            if (t > q && (pr[t] & kb)) chunk_sup |= 1u << t;
                    }
                }
            }
            if (lane == 0) { s_kept = kept; s_done = done; }
        } else {
            // ---- waves 1-7 pool: stage chunk c+1 (transposed), then B2 ----
            int t = tid - 64;                          // 0..447
            if (c + 1 < NCHUNK) {
                int wb2 = wbase + CW;
                for (int pe = t; pe < CW * 256; pe += 448) {
                    int q = pe >> 8, r = (pe & 255) << 1;
                    if (q > (r >> 6)) {                // triangle only (never read otherwise)
                        ulonglong2 v = make_ulonglong2(0ULL, 0ULL);
                        if (wb2 + q < NW && wb2 + (r >> 6) < NW)   // target+source words valid
                            v = *(const ulonglong2*)&diagw[((size_t)(wb2 + q) << 9) + r];
                        *(ulonglong2*)&cblk[nbuf][(q << 9) + r] = v;
                    }
                }
                for (int pe = t; pe < CW * 32; pe += 448) {
                    int e = pe << 1, q = e >> 6;
                    ulonglong2 v = make_ulonglong2(0ULL, 0ULL);
                    if (wb2 + q < NW) v = *(const ulonglong2*)&diagT[((size_t)wb2 << 6) + e];
                    *(ulonglong2*)&ldsT[nbuf][e] = v;
                }
            }
            {
                // B2: kept(c-1) rows into gm[words >= wbase+CW], 16B vectorized
                int w2 = wbase + CW;
                int nw2 = NW - w2;                     // always even
                int nr2 = kB - kA;
                if (c > 0 && nr2 > 0 && nw2 > 0) {
                    int npair = nw2 >> 1;
                    int tot = nr2 * npair;
                    for (int idx = t; idx < tot; idx += 448) {
                        int s = idx / npair, po = idx - s * npair;
                        int row = keptArr[kA + s];
                        ulonglong2 v = *(const ulonglong2*)&rowr[(size_t)row * NW + w2 + (po << 1)];
                        if (v.x) atomicOr(&gm[w2 + (po << 1)], v.x);
                        if (v.y) atomicOr(&gm[w2 + (po << 1) + 1], v.y);
                    }
                }
            }
        }
        __syncthreads();
        kA = kB;
        kB = s_kept;
        if (s_done != 0 || c == NCHUNK - 1) break;
    }
    __syncthreads();

    int kept = s_kept;
    for (int k = tid; k < POSTN; k += 512) {
        float4 bb = make_float4(0.f, 0.f, 0.f, 0.f);
        if (k < kept) bb = sortedbox[keptArr[k]];
        out[k * 5 + 0] = 0.0f;
        out[k * 5 + 1] = bb.x;
        out[k * 5 + 2] = bb.y;
        out[k * 5 + 3] = bb.z;
        out[k * 5 + 4] = bb.w;
    }
}

extern "C" void kernel_launch(void* const* d_in, const int* in_sizes, int n_in,
                              void* d_out, int out_size, void* d_ws, size_t ws_size,
                              hipStream_t stream) {
    const float* scores = (const float*)d_in[0];
    const float* deltas = (const float*)d_in[1];
    const float* iminfo = (const float*)d_in[2];
    char* w = (char*)d_ws;
    // workspace (~5.5 MB). rowr ALIASES boxes+skeys (both dead after rankscatter).
    float4*   boxes = (float4*)w;                                   // [0, 3538944)
    unsigned* skeys = (unsigned*)(w + 3538944);                     // [3538944, 4423680)
    unsigned long long* rowr = (unsigned long long*)w;              // [0, 4524032) alias
    unsigned* meta16 = (unsigned*)(w + 4786176);                    // 16 words
    unsigned long long* cbuf = (unsigned long long*)(w + 4786240);  // [4786240, 4917312)
    float4* sortedbox = (float4*)(w + 4917312);                     // [4917312, 5013568)
    unsigned long long* diagw = (unsigned long long*)(w + 5013568); // [5013568, 5398592)
    unsigned long long* diagT = (unsigned long long*)(w + 5398592); // [5398592, 5446720)
    unsigned* ghist = (unsigned*)(w + 5446720);                     // [5446720, 5479488) 32KB
    float* out = (float*)d_out;

    hipMemsetAsync(ghist, 0, NBIN13 * sizeof(unsigned), stream);    // capture-safe
    decode_kernel<<<NCELL / 256, 256, 0, stream>>>(scores, deltas, iminfo, boxes, skeys, ghist);
    compactT_kernel<<<NCB, 1024, 0, stream>>>(skeys, ghist, meta16, cbuf);
    rankscatter_kernel<<<CAP2 / 32, 256, 0, stream>>>(cbuf, meta16, boxes, sortedbox);
    matrix_kernel<<<dim3(24, 94), 256, 0, stream>>>(sortedbox, rowr, diagw, diagT);
    scan_kernel<<<1, 512, 0, stream>>>(rowr, diagw, diagT, sortedbox, out);
}

// Round 10
// 130.763 us; speedup vs baseline: 1.9292x; 1.0443x over previous
//
#include <hip/hip_runtime.h>

#define NCELL 24576      // 128*192 feature cells
#define NTOT  221184     // NCELL * 9
#define NBIN13 8192      // 13-bit score-key histogram bins (LDS)
#define TOPN  6000
#define POSTN 300
#define NPADR 6016       // padded candidate count (94 words of 64)
#define NW    94         // suppression-mask words per row
#define CW    8          // words per scan chunk (512 ranks)
#define NCHUNK 12        // ceil(94/8)
#define NCB   16         // compaction blocks
#define SLOT  1024       // cbuf slot per compaction block
#define CAP2  (NCB*SLOT) // 16384 total cbuf slots

// ---------------- decode anchors + scores, build sort keys + fused global hist ----------------
// ghist must be zeroed (hipMemsetAsync) before this launch. Each block histograms its own
// 2304 keys in LDS, then flushes nonzero bins via device-scope atomicAdd.
// NOTE (R8 lesson): do NOT fuse these stages with hipLaunchCooperativeKernel -- grid.sync()
// on gfx950 under graph capture cost ~50us per sync (113us kernel, VALUBusy 0.6%, pure stall).
__global__ void decode_kernel(const float* __restrict__ scores,
                              const float* __restrict__ deltas,
                              const float* __restrict__ iminfo,
                              float4* __restrict__ boxes,
                              unsigned* __restrict__ skeys,
                              unsigned* __restrict__ ghist) {
#pragma clang fp contract(off)
    __shared__ unsigned lhist[NBIN13];     // 32 KB
    int tid = threadIdx.x;
    for (int b = tid; b < NBIN13; b += 256) lhist[b] = 0u;
    __syncthreads();
    int c = blockIdx.x * blockDim.x + tid;
    if (c < NCELL) {
        const float AW[9] = {184.f,368.f,736.f,128.f,256.f,512.f, 88.f,176.f,352.f};
        const float AH[9] = { 96.f,192.f,384.f,128.f,256.f,512.f,176.f,352.f,704.f};
        float sx = (float)((c >> 7) << 4);   // (c/128)*16  -- 'ij' meshgrid quirk
        float sy = (float)((c & 127) << 4);  // (c%128)*16
        float imh = iminfo[0], imw = iminfo[1], ims = iminfo[2];
        float xhi = imw - 1.0f, yhi = imh - 1.0f;
        float ms = 16.0f * ims;
        float ctrx = sx + 8.0f, ctry = sy + 8.0f;
        const float* sbase = scores + 9 * NCELL + c;
        const float* dbase = deltas + c;
#pragma unroll
        for (int a = 0; a < 9; ++a) {
            float sc = sbase[a * NCELL];
            float dx = dbase[(4 * a + 0) * NCELL];
            float dy = dbase[(4 * a + 1) * NCELL];
            float dw = dbase[(4 * a + 2) * NCELL];
            float dh = dbase[(4 * a + 3) * NCELL];
            float pcx = dx * AW[a] + ctrx;
            float pcy = dy * AH[a] + ctry;
            float pw = expf(dw) * AW[a];
            float ph = expf(dh) * AH[a];
            float x1 = pcx - 0.5f * pw;
            float y1 = pcy - 0.5f * ph;
            float x2 = pcx + 0.5f * pw;
            float y2 = pcy + 0.5f * ph;
            x1 = fminf(fmaxf(x1, 0.0f), xhi);
            x2 = fminf(fmaxf(x2, 0.0f), xhi);
            y1 = fminf(fmaxf(y1, 0.0f), yhi);
            y2 = fminf(fmaxf(y2, 0.0f), yhi);
            bool valid = ((x2 - x1 + 1.0f) >= ms) && ((y2 - y1 + 1.0f) >= ms);
            unsigned u = __float_as_uint(sc);
            unsigned key = (u & 0x80000000u) ? ~u : (u | 0x80000000u);
            if (!valid) key = 0x007FFFFFu;   // sort key of -inf
            boxes[a * NCELL + c] = make_float4(x1, y1, x2, y2);
            skeys[a * NCELL + c] = key;
            atomicAdd(&lhist[key >> 19], 1u);
        }
    }
    __syncthreads();
    for (int b = tid; b < NBIN13; b += 256) {
        unsigned v = lhist[b];
        if (v) atomicAdd(&ghist[b], v);      // device-scope, cross-XCD safe
    }
}

// ---------------- per-block T-find (from precomputed ghist) + slice compact (16 blocks) -------
__global__ __launch_bounds__(1024) void compactT_kernel(const unsigned* __restrict__ skeys,
                                                        const unsigned* __restrict__ ghist,
                                                        unsigned* __restrict__ meta16,
                                                        unsigned long long* __restrict__ cbuf) {
    __shared__ unsigned hist[NBIN13];      // 32 KB
    __shared__ unsigned psum[1024];
    __shared__ unsigned csum[256];
    __shared__ unsigned sB, sAbove, sT, sCount;
    int tid = threadIdx.x, bid = blockIdx.x;
    // load the finished histogram (2 x uint4 per thread)
    {
        const uint4* gh4 = (const uint4*)ghist;
        uint4* h4 = (uint4*)hist;
        for (int q = tid; q < NBIN13 / 4; q += 1024) h4[q] = gh4[q];
    }
    if (tid == 0) sCount = 0u;
    __syncthreads();
    // threshold T: cum(>=T) >= 6000, cum(>T) < 6000  (identical in every block)
    unsigned s = 0;
#pragma unroll
    for (int q = 0; q < 8; ++q) s += hist[tid * 8 + q];
    psum[tid] = s;
    __syncthreads();
    if (tid < 256)
        csum[tid] = psum[tid * 4] + psum[tid * 4 + 1] + psum[tid * 4 + 2] + psum[tid * 4 + 3];
    __syncthreads();
    if (tid < 64) {
        int lane = tid;
        unsigned c0 = csum[lane * 4 + 0], c1 = csum[lane * 4 + 1];
        unsigned c2 = csum[lane * 4 + 2], c3 = csum[lane * 4 + 3];
        unsigned ls = c0 + c1 + c2 + c3;
        unsigned v = ls;
#pragma unroll
        for (int o = 1; o < 64; o <<= 1) {
            unsigned t = __shfl_down(v, o, 64);
            if (lane + o < 64) v += t;
        }
        unsigned sufExcl = v - ls;
        unsigned a3 = sufExcl;
        unsigned a2 = a3 + c3;
        unsigned a1 = a2 + c2;
        unsigned a0 = a1 + c1;
        if (a0 < TOPN && a0 + c0 >= TOPN) { sB = lane * 4 + 0; sAbove = a0; }
        if (a1 < TOPN && a1 + c1 >= TOPN) { sB = lane * 4 + 1; sAbove = a1; }
        if (a2 < TOPN && a2 + c2 >= TOPN) { sB = lane * 4 + 2; sAbove = a2; }
        if (a3 < TOPN && a3 + c3 >= TOPN) { sB = lane * 4 + 3; sAbove = a3; }
    }
    __syncthreads();
    if (tid < 32) {
        unsigned B = sB, above = sAbove;
        unsigned h = hist[B * 32 + tid];
        unsigned v = h;
#pragma unroll
        for (int o = 1; o < 32; o <<= 1) {
            unsigned t = __shfl_down(v, o, 64);
            if (tid + o < 32) v += t;
        }
        unsigned sufExcl = v - h;
        unsigned ab = above + sufExcl;
        if (ab < TOPN && ab + h >= TOPN) sT = B * 32 + tid;
    }
    __syncthreads();
    // compact OWN slice into private slot (LDS-local positions, no global atomics)
    unsigned T = sT;
    int base = bid * (NTOT / NCB);                  // 13824-element slice
    const uint4* s4b = (const uint4*)(skeys + base);
    for (int q = tid; q < (NTOT / NCB) / 4; q += 1024) {
        uint4 u = s4b[q];
        unsigned k4[4] = {u.x, u.y, u.z, u.w};
#pragma unroll
        for (int k = 0; k < 4; ++k) {
            if ((k4[k] >> 19) >= T) {
                unsigned lp = atomicAdd(&sCount, 1u);
                if (lp < SLOT) {
                    int m = base + 4 * q + k;
                    unsigned n = (unsigned)((m % NCELL) * 9 + (m / NCELL));
                    cbuf[(bid << 10) + lp] =
                        ((unsigned long long)k4[k] << 32) | (unsigned long long)(~n);
                }
            }
        }
    }
    __syncthreads();
    unsigned cnt = sCount; if (cnt > SLOT) cnt = SLOT;
    for (int e = cnt + tid; e < SLOT; e += 1024) cbuf[(bid << 10) + e] = 0ULL;  // pad
    if (tid == 0) meta16[bid] = cnt;
}

// ---------------- rank by counting + scatter over slotted cbuf ----------------
__global__ __launch_bounds__(256) void rankscatter_kernel(const unsigned long long* __restrict__ cbuf,
                                                          const unsigned* __restrict__ meta16,
                                                          const float4* __restrict__ boxes,
                                                          float4* __restrict__ sortedbox) {
    __shared__ __align__(16) unsigned long long jk[512];
    __shared__ unsigned scnt[NCB];
    int tid = threadIdx.x;
    if (tid < NCB) scnt[tid] = meta16[tid];
    __syncthreads();
    int i = blockIdx.x * 32 + (tid >> 3);
    int slice = tid & 7;
    unsigned long long ki = cbuf[i];
    unsigned cr = 0;
    for (int jt = 0; jt < CAP2 / 512; ++jt) {
        int b = jt >> 1;
        unsigned cb = scnt[b];
        if ((jt & 1) ? (cb <= 512u) : (cb == 0u)) continue;   // block-uniform skip
        __syncthreads();
        *(ulonglong2*)&jk[tid << 1] = *(const ulonglong2*)&cbuf[(jt << 9) + (tid << 1)];
        __syncthreads();
#pragma unroll 8
        for (int j = 0; j < 64; ++j) cr += (jk[slice + (j << 3)] > ki) ? 1u : 0u;
    }
    cr += __shfl_down(cr, 4, 8);
    cr += __shfl_down(cr, 2, 8);
    cr += __shfl_down(cr, 1, 8);
    if (slice == 0 && ki != 0ULL && cr < NPADR) {
        unsigned n = ~(unsigned)ki;
        unsigned m = (n % 9u) * (unsigned)NCELL + (n / 9u);
        sortedbox[cr] = boxes[m];
    }
}

// ---------------- all-pairs suppression matrix: word-per-thread ----------------
// grid (24, 94): blockIdx.y = 64-row i-tile; blockIdx.x = one 256-col j-tile.
// rowr: row-major words, only w >= row's diag word (B1/B2 read those).
// diagw holds TRANSPOSED chunk-triangle 64x64 blocks: slot [(w<<9)+(qs<<6)+j] =
// column j of block (qs -> w), qs < w within the chunk. Exact-diag transpose -> diagT.
// The per-j (jg0+j > i) predicate is hoisted: identically true for w > i>>6; the single
// diagonal word is masked after the loop (bit-exact vs per-j predicate).
__global__ __launch_bounds__(256) void matrix_kernel(const float4* __restrict__ sortedbox,
                                                     unsigned long long* __restrict__ rowr,
                                                     unsigned long long* __restrict__ diagw,
                                                     unsigned long long* __restrict__ diagT) {
#pragma clang fp contract(off)
    __shared__ float4 jb[256];
    __shared__ float  ja[256];
    int tid = threadIdx.x;
    int lane = tid & 63, wave = tid >> 6;
    int i0 = blockIdx.y << 6;
    int i = i0 + lane;
    int w = (blockIdx.x << 2) + wave;
    int jbase = blockIdx.x << 8;
    unsigned long long word = 0ULL;

    if (jbase + 255 > i0) {                  // tile not entirely below diagonal
        int jg = jbase + tid;
        float4 v = (jg < NPADR) ? sortedbox[jg] : make_float4(0.f, 0.f, 0.f, 0.f);
        jb[tid] = v;
        ja[tid] = (v.z - v.x) * (v.w - v.y);
        __syncthreads();
        if (w < NW && ((w << 6) + 63) > i) { // this word has bits above the diagonal
            float4 bi = sortedbox[i];
            float ai = (bi.z - bi.x) * (bi.w - bi.y);
            int jl0 = wave << 6;
#pragma unroll 8
            for (int j = 0; j < 64; ++j) {
                float4 bj = jb[jl0 + j];
                float aj = ja[jl0 + j];
                float iw = fminf(bi.z, bj.z) - fmaxf(bi.x, bj.x);
                float ih = fminf(bi.w, bj.w) - fmaxf(bi.y, bj.y);
                iw = fmaxf(iw, 0.0f);
                ih = fmaxf(ih, 0.0f);
                float inter = iw * ih;
                float denom = fmaxf(ai + aj - inter, 1e-9f);
                bool sup = (inter / denom > 0.7f);
                word |= (unsigned long long)sup << j;
            }
            if (w == (i >> 6))               // diagonal word: keep only j > lane bits
                word &= (lane == 63) ? 0ULL : (~0ULL << (lane + 1));
        }
    }
    if (w < NW) {
        if (w >= (i >> 6))                   // above/diag words only (sub-diag never read)
            rowr[(size_t)i * NW + w] = word;
        if ((i >> 9) == (w >> 3) && w >= (i >> 6)) {
            // chunk-region block at/above diagonal: transpose via 64 ballots
            unsigned long long col = 0ULL;
#pragma unroll
            for (int jbit = 0; jbit < 64; ++jbit) {
                unsigned long long m = __ballot((word >> jbit) & 1ULL);
                if (lane == jbit) col = m;
            }
            if (w == (i >> 6))
                diagT[((size_t)w << 6) + lane] = col;         // exact diag block
            else
                diagw[((size_t)w << 9) + (i & 511)] = col;    // transposed triangle block
        }
    }
}

// ---------------- greedy scan: transposed-propagate resolve ∥ stage+B2 pool, then B1 ----------
// (exact R7 structure -- the R9 inline-fold variant measured +0.9us and was reverted)
// 512 threads. Per chunk c:
//   wave0  : prefetch gm[wbase..wbase+7] (one LDS round), then per word q: fixed-point
//            resolve (live = ~(gml|ballot(chunk_sup bit q))); propagate to later words via
//            TRANSPOSED blocks: lane j tests cblkT[t][q][j] & kb -- 8 independent LDS reads,
//            one latency round, no bit-extraction, no gm writes (chunk-c gm dead after A(c)).
//   waves1-7 pool: stage chunk c+1 (transposed triangle cblk + ldsT, 16B loads), then B2:
//            kept(c-1) rows -> gm[words >= wbase+CW] from row-major rowr.
//   barrier; B1 (all 512): kept(c) -> next-chunk words; barrier.
// Coverage: kept(c-1)->chunk c via B1(c-1); kept(k<=c-2)->chunk c via B2@A(k+1); in-chunk
// via chunk_sup. Races: helpers atomicOr only words >= wbase+CW (gml prefetch unaffected);
// keptArr reads [kA,kB) disjoint from resolve writes [kB,...); buffers double-buffered.
__global__ __launch_bounds__(512) void scan_kernel(const unsigned long long* __restrict__ rowr,
                                                   const unsigned long long* __restrict__ diagw,
                                                   const unsigned long long* __restrict__ diagT,
                                                   const float4* __restrict__ sortedbox,
                                                   float* __restrict__ out) {
    __shared__ __align__(16) unsigned long long cblk[2][CW * 512]; // 64 KB transposed blocks
    __shared__ __align__(16) unsigned long long ldsT[2][CW * 64];  // 8 KB diagT dbuf
    __shared__ unsigned long long gm[128];
    __shared__ int keptArr[POSTN];
    __shared__ int s_kept, s_done;
    int tid = threadIdx.x;
    int lane = tid & 63, wave = tid >> 6;

    if (tid < 128) gm[tid] = (tid == 93) ? ~((1ULL << 48) - 1) : 0ULL; // ranks>=6000 dead
    if (tid == 0) { s_kept = 0; s_done = 0; }
    // stage chunk 0: triangle cblkT + ldsT, 16B vectorized (all 512 threads)
    for (int pe = tid; pe < CW * 256; pe += 512) {
        int q = pe >> 8, r = (pe & 255) << 1;
        if (q > (r >> 6))
            *(ulonglong2*)&cblk[0][(q << 9) + r] =
                *(const ulonglong2*)&diagw[((size_t)q << 9) + r];
    }
    for (int pe = tid; pe < CW * 32; pe += 512) {
        int e = pe << 1;
        *(ulonglong2*)&ldsT[0][e] = *(const ulonglong2*)&diagT[e];
    }
    __syncthreads();

    int kA = 0;  // kept count before chunk c-1's resolve
    int kB = 0;  // kept count before chunk c's resolve
    for (int c = 0; c < NCHUNK; ++c) {
        int buf = c & 1, nbuf = buf ^ 1;
        int wbase = c * CW;
        if (wave == 0) {
            // ---- resolve chunk c: transposed propagate, register chunk state ----
            unsigned long long dgT[CW];
            unsigned long long gml[CW];
#pragma unroll
            for (int q = 0; q < CW; ++q) dgT[q] = ldsT[buf][(q << 6) + lane];
#pragma unroll
            for (int q = 0; q < CW; ++q) gml[q] = (wbase + q < NW) ? gm[wbase + q] : ~0ULL;
            unsigned long long lowmask = (1ULL << lane) - 1ULL;
            unsigned chunk_sup = 0;      // bit t: this lane suppressed in word t by chunk kept
            int kept = kB;
            int done = 0;
            int qmax = (NW - wbase < CW) ? (NW - wbase) : CW;
            for (int q = 0; q < qmax; ++q) {
                unsigned long long csup = __ballot((chunk_sup >> q) & 1u);
                unsigned long long live = ~(gml[q] | csup);
                if (wbase + q == NW - 1) live &= (1ULL << 48) - 1;
                if (!live) continue;
                bool alive = (live >> lane) & 1ULL;
                unsigned long long x = live;
                for (;;) {
                    bool sup = (dgT[q] & x & lowmask) != 0ULL;
                    unsigned long long xn = __ballot(alive && !sup);
                    if (xn == x) break;
                    x = xn;
                }
                unsigned long long kb = x;
                if (kb) {
                    int nk = __popcll(kb);
                    int myr = __popcll(kb & lowmask);
                    if (((kb >> lane) & 1ULL) && (kept + myr < POSTN))
                        keptArr[kept + myr] = ((wbase + q) << 6) + lane;
                    kept += nk;
                    if (kept >= POSTN) { kept = POSTN; done = 1; break; }
                    if (q < CW - 1) {
                        // one parallel LDS round: lane j tests column j of each later word
                        unsigned long long pr[CW];
#pragma unroll
                        for (int t = 0; t < CW; ++t)
                            pr[t] = cblk[buf][(t << 9) + (q << 6) + lane];
#pragma unroll
                        for (int t = 0; t < CW; ++t)
                            if (t > q && (pr[t] & kb)) chunk_sup |= 1u << t;
                    }
                }
            }
            if (lane == 0) { s_kept = kept; s_done = done; }
        } else {
            // ---- waves 1-7 pool: stage chunk c+1 (transposed), then B2 ----
            int t = tid - 64;                          // 0..447
            if (c + 1 < NCHUNK) {
                int wb2 = wbase + CW;
                for (int pe = t; pe < CW * 256; pe += 448) {
                    int q = pe >> 8, r = (pe & 255) << 1;
                    if (q > (r >> 6)) {                // triangle only (never read otherwise)
                        ulonglong2 v = make_ulonglong2(0ULL, 0ULL);
                        if (wb2 + q < NW && wb2 + (r >> 6) < NW)   // target+source words valid
                            v = *(const ulonglong2*)&diagw[((size_t)(wb2 + q) << 9) + r];
                        *(ulonglong2*)&cblk[nbuf][(q << 9) + r] = v;
                    }
                }
                for (int pe = t; pe < CW * 32; pe += 448) {
                    int e = pe << 1, q = e >> 6;
                    ulonglong2 v = make_ulonglong2(0ULL, 0ULL);
                    if (wb2 + q < NW) v = *(const ulonglong2*)&diagT[((size_t)wb2 << 6) + e];
                    *(ulonglong2*)&ldsT[nbuf][e] = v;
                }
            }
            {
                // B2: kept(c-1) rows into gm[words >= wbase+CW], 16B vectorized
                int w2 = wbase + CW;
                int nw2 = NW - w2;                     // always even
                int nr2 = kB - kA;
                if (c > 0 && nr2 > 0 && nw2 > 0) {
                    int npair = nw2 >> 1;
                    int tot = nr2 * npair;
                    for (int idx = t; idx < tot; idx += 448) {
                        int s = idx / npair, po = idx - s * npair;
                        int row = keptArr[kA + s];
                        ulonglong2 v = *(const ulonglong2*)&rowr[(size_t)row * NW + w2 + (po << 1)];
                        if (v.x) atomicOr(&gm[w2 + (po << 1)], v.x);
                        if (v.y) atomicOr(&gm[w2 + (po << 1) + 1], v.y);
                    }
                }
            }
        }
        __syncthreads();
        int keptNow = s_kept;
        bool fin = (s_done != 0) || (c == NCHUNK - 1);
        if (!fin && keptNow > kB) {
            // ---- B1 (all 512 threads): kept(c) rows -> next-chunk words, 16B vectorized ----
            int w1 = wbase + CW;
            int nw1 = NW - w1; if (nw1 > CW) nw1 = CW; // always even
            int npair1 = nw1 >> 1;
            int po = tid & 3;
            for (int s = kB + (tid >> 2); s < keptNow; s += 128) {
                if (po < npair1) {
                    int row = keptArr[s];
                    ulonglong2 v = *(const ulonglong2*)&rowr[(size_t)row * NW + w1 + (po << 1)];
                    if (v.x) atomicOr(&gm[w1 + (po << 1)], v.x);
                    if (v.y) atomicOr(&gm[w1 + (po << 1) + 1], v.y);
                }
            }
        }
        kA = kB;
        kB = keptNow;
        if (fin) break;
        __syncthreads();
    }
    __syncthreads();

    int kept = s_kept;
    for (int k = tid; k < POSTN; k += 512) {
        float4 bb = make_float4(0.f, 0.f, 0.f, 0.f);
        if (k < kept) bb = sortedbox[keptArr[k]];
        out[k * 5 + 0] = 0.0f;
        out[k * 5 + 1] = bb.x;
        out[k * 5 + 2] = bb.y;
        out[k * 5 + 3] = bb.z;
        out[k * 5 + 4] = bb.w;
    }
}

extern "C" void kernel_launch(void* const* d_in, const int* in_sizes, int n_in,
                              void* d_out, int out_size, void* d_ws, size_t ws_size,
                              hipStream_t stream) {
    const float* scores = (const float*)d_in[0];
    const float* deltas = (const float*)d_in[1];
    const float* iminfo = (const float*)d_in[2];
    char* w = (char*)d_ws;
    // workspace (~5.5 MB). rowr ALIASES boxes+skeys (both dead after rankscatter).
    float4*   boxes = (float4*)w;                                   // [0, 3538944)
    unsigned* skeys = (unsigned*)(w + 3538944);                     // [3538944, 4423680)
    unsigned long long* rowr = (unsigned long long*)w;              // [0, 4524032) alias
    unsigned* meta16 = (unsigned*)(w + 4786176);                    // 16 words
    unsigned long long* cbuf = (unsigned long long*)(w + 4786240);  // [4786240, 4917312)
    float4* sortedbox = (float4*)(w + 4917312);                     // [4917312, 5013568)
    unsigned long long* diagw = (unsigned long long*)(w + 5013568); // [5013568, 5398592)
    unsigned long long* diagT = (unsigned long long*)(w + 5398592); // [5398592, 5446720)
    unsigned* ghist = (unsigned*)(w + 5446720);                     // [5446720, 5479488) 32KB
    float* out = (float*)d_out;

    hipMemsetAsync(ghist, 0, NBIN13 * sizeof(unsigned), stream);    // capture-safe
    decode_kernel<<<NCELL / 256, 256, 0, stream>>>(scores, deltas, iminfo, boxes, skeys, ghist);
    compactT_kernel<<<NCB, 1024, 0, stream>>>(skeys, ghist, meta16, cbuf);
    rankscatter_kernel<<<CAP2 / 32, 256, 0, stream>>>(cbuf, meta16, boxes, sortedbox);
    matrix_kernel<<<dim3(24, 94), 256, 0, stream>>>(sortedbox, rowr, diagw, diagT);
    scan_kernel<<<1, 512, 0, stream>>>(rowr, diagw, diagT, sortedbox, out);
}